// Round 3
// baseline (376.509 us; speedup 1.0000x reference)
//
#include <hip/hip_runtime.h>

// FastAttention (Performer linear attention), MI355X gfx950.
// B=4 L=4096 H=16 D=E=64 M=256, all fp32 in/out. bf16 MFMA internally.
//
// R3: fix the k1 epilogue memory pattern. R2's counters showed k1 duration =
// traffic x pattern-limited BW (410 MB @ 2.5 TB/s = 165 us): the 16B-scattered
// partial stores caused 4x write amplification + RFO fetch (~240 MB of junk).
// Now: after the K-loop, acc is transposed through LDS (reusing the tile
// arena) into [e][m] fp32 and stored with fully-coalesced f4v writes.
// k3: split the 8-deep GEMM4 MFMA dependency chain into 2 accumulators.

#define LL 4096
#define HH 16
#define DD 64
#define EE 64
#define MM 256
#define SCALE 0.35355339059327378f  // 64^-0.25

typedef __attribute__((ext_vector_type(8))) __bf16 bf8v;
typedef __attribute__((ext_vector_type(4))) __bf16 bf4v;
typedef __attribute__((ext_vector_type(4))) float f4v;

__device__ __forceinline__ __bf16 f2bf(float f) {
  // round-to-nearest-even fp32 -> bf16 (inputs are normal floats)
  union { float f; unsigned u; } x; x.f = f;
  unsigned r = (x.u + 0x7FFFu + ((x.u >> 16) & 1u)) >> 16;
  union { unsigned short s; __bf16 b; } y; y.s = (unsigned short)r;
  return y.b;
}

// Barrier with LDS-visibility only: does NOT drain vmcnt, so prefetched global
// loads stay in flight across it.
__device__ __forceinline__ void barrier_lgkm() {
  asm volatile("s_waitcnt lgkmcnt(0)" ::: "memory");
  __builtin_amdgcn_s_barrier();
  asm volatile("" ::: "memory");
}

#define MFMA16(a, b, c) __builtin_amdgcn_mfma_f32_16x16x32_bf16(a, b, c, 0, 0, 0)

// ws layout (floats), partial path:
//   [ pkv: 8 chunk * 64 bh * 64 e * 256 m ][ pks: 8 * 64 * 256 ]
//   [ kv : 64 bh * 64 e * 256 m ][ ks: 64 * 256 ]
#define PKV_ELEMS (8ull * 64 * 64 * 256)  // 8,388,608
#define PKS_ELEMS (8ull * 64 * 256)       //   131,072
#define KV_ELEMS (64ull * 64 * 256)       // 1,048,576
#define KS_ELEMS (64ull * 256)            //    16,384
#define WS_PART_BYTES ((PKV_ELEMS + PKS_ELEMS + KV_ELEMS + KS_ELEMS) * 4)
#define WS_ATOMIC_BYTES ((KV_ELEMS + KS_ELEMS) * 4)

// LDS arena (bytes): kt2 [2][64*72]bf16 = 18432 | vt2 [2][64*68]bf16 = 17408
// | kft [256*72]bf16 = 36864  -> total 72704.
// Epilogue reuses bytes [0, 66560) as float [64 e][260 m-padded].
#define ARENA_BYTES 72704
#define KT_OFF 0
#define VT_OFF 18432
#define KFT_OFF 35840

// ---------------------------------------------------------------------------
// Kernel 1: build KV and Ksum (per-chunk partials, or atomic fallback).
// grid (8 chunks, 64 bh), 512 threads (8 waves). 8 iters of 64 rows.
// Per wave: m-band [32*w, 32*w+32).
// Pipeline: dbuf kt/vt, depth-2 register prefetch, ONE raw barrier per iter.
// Epilogue: LDS-transpose acc -> [e][m] fp32, coalesced f4v global stores.
// ---------------------------------------------------------------------------
__global__ __launch_bounds__(512, 4)
void k1_kv(const float* __restrict__ kin, const float* __restrict__ vin,
           const float* __restrict__ pin,
           float* __restrict__ pkv, float* __restrict__ pks,
           float* __restrict__ kv, float* __restrict__ ks, int partials) {
  __shared__ alignas(16) char arena[ARENA_BYTES];
  __bf16* ktA[2] = {(__bf16*)(arena + KT_OFF), (__bf16*)(arena + KT_OFF) + 64 * 72};
  __bf16* vtA[2] = {(__bf16*)(arena + VT_OFF), (__bf16*)(arena + VT_OFF) + 64 * 68};
  __bf16* kft = (__bf16*)(arena + KFT_OFF);

  const int tid = threadIdx.x;
  const int w = tid >> 6;      // wave 0..7, m-band 32*w
  const int lane = tid & 63;
  const int qd = lane >> 4;
  const int nn = lane & 15;
  const int bh = blockIdx.y;
  const int b = bh >> 4, h = bh & 15;
  const int l0 = blockIdx.x * 512;

  const size_t bhbase = (size_t)b * LL * HH * DD + (size_t)h * DD;
  // staging map: 16 threads cover one 256B row; each thread owns rows r0, r0+32.
  const int r0 = tid >> 4;          // 0..31
  const int c0 = (tid & 15) * 4;    // float col 0..60

  const float* gk = kin + bhbase + (size_t)(l0 + r0) * (HH * DD) + c0;
  const float* gv = vin + bhbase + (size_t)(l0 + r0) * (HH * DD) + c0;
  const size_t RSTEP = (size_t)32 * HH * DD;  // +32 rows
  const size_t TSTEP = (size_t)64 * HH * DD;  // +64 rows (next tile)

  // ---- issue tiles 0,1 (depth-2 prefetch) ----
  f4v kr[2][2], vr[2][2];
  kr[0][0] = *(const f4v*)gk;          kr[0][1] = *(const f4v*)(gk + RSTEP);
  vr[0][0] = *(const f4v*)gv;          vr[0][1] = *(const f4v*)(gv + RSTEP);
  gk += TSTEP; gv += TSTEP;
  kr[1][0] = *(const f4v*)gk;          kr[1][1] = *(const f4v*)(gk + RSTEP);
  vr[1][0] = *(const f4v*)gv;          vr[1][1] = *(const f4v*)(gv + RSTEP);
  gk += TSTEP; gv += TSTEP;

  // P fragments (B-operand of GEMM1): rows m = 32*w + mt*16 + nn, k d = c*32+qd*8+j.
  bf8v pf[2][2];
#pragma unroll
  for (int mt = 0; mt < 2; ++mt) {
    const float* pr = pin + (size_t)(32 * w + mt * 16 + nn) * DD;
#pragma unroll
    for (int c = 0; c < 2; ++c) {
      bf8v t;
#pragma unroll
      for (int j = 0; j < 8; ++j) t[j] = f2bf(pr[c * 32 + qd * 8 + j] * SCALE);
      pf[mt][c] = t;
    }
  }

  f4v acc[2][4];  // [mt][et]: C rows m = 32w+mt*16+4qd+r, cols e = et*16+nn
#pragma unroll
  for (int i = 0; i < 2; ++i)
#pragma unroll
    for (int j = 0; j < 4; ++j) acc[i][j] = (f4v){0.f, 0.f, 0.f, 0.f};
  float ksum[2] = {0.f, 0.f};

  auto stage = [&](int buf, const f4v* kk, const f4v* vv) {
    __bf16* ktb = ktA[buf];
    __bf16* vtb = vtA[buf];
#pragma unroll
    for (int rr = 0; rr < 2; ++rr) {
      bf4v a, c;
#pragma unroll
      for (int j = 0; j < 4; ++j) { a[j] = f2bf(kk[rr][j]); c[j] = f2bf(vv[rr][j]); }
      *(bf4v*)&ktb[(r0 + 32 * rr) * 72 + c0] = a;
      *(bf4v*)&vtb[(r0 + 32 * rr) * 68 + c0] = c;
    }
  };

  auto gemm12 = [&](int buf) {
    const __bf16* ktb = ktA[buf];
    const __bf16* vtb = vtA[buf];
    // GEMM1: C[l][m] = kt . P^T ; phi ; ksum ; write kft[m][l] (own band, b64)
#pragma unroll
    for (int lt = 0; lt < 4; ++lt) {
      bf8v a0 = *(const bf8v*)&ktb[(lt * 16 + nn) * 72 + qd * 8];
      bf8v a1 = *(const bf8v*)&ktb[(lt * 16 + nn) * 72 + 32 + qd * 8];
#pragma unroll
      for (int mt = 0; mt < 2; ++mt) {
        f4v cc = (f4v){0.f, 0.f, 0.f, 0.f};
        cc = MFMA16(a0, pf[mt][0], cc);
        cc = MFMA16(a1, pf[mt][1], cc);
        // lane holds rows l = lt*16+4qd+r, col m = 32w+mt*16+nn
        bf4v pk4;
#pragma unroll
        for (int r = 0; r < 4; ++r) {
          float ph = fmaxf(cc[r], 0.f) + 1e-3f;
          ksum[mt] += ph;
          pk4[r] = f2bf(ph);
        }
        *(bf4v*)&kft[(32 * w + mt * 16 + nn) * 72 + lt * 16 + qd * 4] = pk4;
      }
    }
    // GEMM2: acc[m][e] += kft(own band) . v  (same-wave kft RAW via lgkmcnt)
#pragma unroll
    for (int c = 0; c < 2; ++c) {
      bf8v af0 = *(const bf8v*)&kft[(32 * w + nn) * 72 + c * 32 + qd * 8];
      bf8v af1 = *(const bf8v*)&kft[(32 * w + 16 + nn) * 72 + c * 32 + qd * 8];
#pragma unroll
      for (int et = 0; et < 4; ++et) {
        bf8v bv;  // B[k=l][n=e]: column of vt (8 scalar reads, ~2-way)
#pragma unroll
        for (int j = 0; j < 8; ++j) bv[j] = vtb[(c * 32 + qd * 8 + j) * 68 + et * 16 + nn];
        acc[0][et] = MFMA16(af0, bv, acc[0][et]);
        acc[1][et] = MFMA16(af1, bv, acc[1][et]);
      }
    }
  };

  // prologue: stage tile 0, make visible
  stage(0, kr[0], vr[0]);
  barrier_lgkm();

#pragma unroll
  for (int t = 0; t < 8; ++t) {
    const int cur = t & 1;
    // issue loads for tile t+2 into the reg set freed at end of last iter
    if (t + 2 < 8) {
      kr[cur][0] = *(const f4v*)gk;      kr[cur][1] = *(const f4v*)(gk + RSTEP);
      vr[cur][0] = *(const f4v*)gv;      vr[cur][1] = *(const f4v*)(gv + RSTEP);
      gk += TSTEP; gv += TSTEP;
    }
    gemm12(cur);
    if (t + 1 < 8) {
      stage(cur ^ 1, kr[cur ^ 1], vr[cur ^ 1]);  // compiler waits vmcnt here
      barrier_lgkm();
    }
  }

  // ---- epilogue ----
  if (partials) {
    // 1) all waves done reading kt/vt/kft -> arena reusable
    barrier_lgkm();
    float* ep = (float*)arena;  // [64 e][260] fp32 (padded row, bank-spread)
#pragma unroll
    for (int mt = 0; mt < 2; ++mt)
#pragma unroll
      for (int et = 0; et < 4; ++et)
        *(f4v*)&ep[(et * 16 + nn) * 260 + 32 * w + mt * 16 + 4 * qd] = acc[mt][et];
    barrier_lgkm();
    // 2) coalesced readback + dense global stores: 4096 f4v = [e][m] slab.
    //    Consecutive lanes -> consecutive f4v -> 8 KB contiguous per step.
    float* dst = pkv + (size_t)(blockIdx.x * 64 + bh) * (64 * 256);
#pragma unroll
    for (int rr = 0; rr < 8; ++rr) {
      int f = tid + 512 * rr;       // 0..4095
      int e = f >> 6;               // 0..63
      int m4 = f & 63;              // f4v index within e-row
      f4v val = *(const f4v*)&ep[e * 260 + m4 * 4];
      ((f4v*)dst)[f] = val;
    }
    // Ksum partials: dense 64B-per-wave stores
#pragma unroll
    for (int mt = 0; mt < 2; ++mt) {
      float s = ksum[mt];
      s += __shfl_xor(s, 16, 64);
      s += __shfl_xor(s, 32, 64);
      if (lane < 16)
        pks[(size_t)(blockIdx.x * 64 + bh) * 256 + 32 * w + mt * 16 + lane] = s;
    }
  } else {
    float* kvb = kv + (size_t)bh * (64 * 256);
#pragma unroll
    for (int mt = 0; mt < 2; ++mt)
#pragma unroll
      for (int et = 0; et < 4; ++et)
#pragma unroll
        for (int r = 0; r < 4; ++r) {
          int m = 32 * w + mt * 16 + 4 * qd + r;
          int e = et * 16 + nn;
          atomicAdd(&kvb[e * 256 + m], acc[mt][et][r]);
        }
#pragma unroll
    for (int mt = 0; mt < 2; ++mt) {
      float s = ksum[mt];
      s += __shfl_xor(s, 16, 64);
      s += __shfl_xor(s, 32, 64);
      if (lane < 16) atomicAdd(&ks[bh * 256 + 32 * w + mt * 16 + lane], s);
    }
  }
}

// ---------------------------------------------------------------------------
// Kernel 2: reduce 8 chunk-partials -> final KV / Ksum. Pure streaming.
// grid 1040 x 256: 262144 f4v of KV + 4096 f4v of Ksum.
// ---------------------------------------------------------------------------
__global__ __launch_bounds__(256)
void k2_red(const float* __restrict__ pkv, const float* __restrict__ pks,
            float* __restrict__ kv, float* __restrict__ ks) {
  const int idx = blockIdx.x * 256 + threadIdx.x;
  if (idx < 262144) {
    f4v s = (f4v){0.f, 0.f, 0.f, 0.f};
#pragma unroll
    for (int x = 0; x < 8; ++x) s += ((const f4v*)pkv)[(size_t)x * 262144 + idx];
    ((f4v*)kv)[idx] = s;
  } else {
    const int j = idx - 262144;  // < 4096
    f4v s = (f4v){0.f, 0.f, 0.f, 0.f};
#pragma unroll
    for (int x = 0; x < 8; ++x) s += ((const f4v*)pks)[x * 4096 + j];
    ((f4v*)ks)[j] = s;
  }
}

// ---------------------------------------------------------------------------
// Kernel 3: out = (phi(q) @ KV) / (phi(q) . (Ksum+1e-6)).
// grid (8, 64), 512 threads (8 waves = wm 0..3 x wl 0..1), 8 iters of 64 rows.
// dbuf qt, depth-2 prefetch, 2 raw barriers/iter. GEMM4 MFMA chain split in 2.
// ---------------------------------------------------------------------------
__global__ __launch_bounds__(512, 4)
void k3_out(const float* __restrict__ qin, const float* __restrict__ pin,
            const float* __restrict__ kv, const float* __restrict__ ksm,
            float* __restrict__ out) {
  __shared__ __bf16 qt[2][64 * 72];  // q tile [l][d]
  __shared__ __bf16 qf[64 * 264];    // phi(q) [l][m], stride 264
  __shared__ float denp[256];        // den partials [wm][l]
  __shared__ float ksume[256];       // Ksum + 1e-6

  const int tid = threadIdx.x;
  const int w = tid >> 6;
  const int wm = w & 3;
  const int wl = w >> 2;
  const int lane = tid & 63;
  const int qd = lane >> 4;
  const int nn = lane & 15;
  const int bh = blockIdx.y;
  const int b = bh >> 4, h = bh & 15;
  const int l0 = blockIdx.x * 512;
  const int lt0 = 2 * wl;

  const size_t bhbase = (size_t)b * LL * HH * DD + (size_t)h * DD;
  const int r0 = tid >> 4;
  const int c0 = (tid & 15) * 4;

  const float* gq = qin + bhbase + (size_t)(l0 + r0) * (HH * DD) + c0;
  const size_t RSTEP = (size_t)32 * HH * DD;
  const size_t TSTEP = (size_t)64 * HH * DD;

  // ---- issue q tiles 0,1 ----
  f4v qr[2][2];
  qr[0][0] = *(const f4v*)gq;  qr[0][1] = *(const f4v*)(gq + RSTEP);
  gq += TSTEP;
  qr[1][0] = *(const f4v*)gq;  qr[1][1] = *(const f4v*)(gq + RSTEP);
  gq += TSTEP;

  // P fragments (A-operand of GEMM3': rows m = 64*wm + mt*16 + nn).
  bf8v pf[4][2];
#pragma unroll
  for (int mt = 0; mt < 4; ++mt) {
    const float* pr = pin + (size_t)(64 * wm + mt * 16 + nn) * DD;
#pragma unroll
    for (int c = 0; c < 2; ++c) {
      bf8v t;
#pragma unroll
      for (int j = 0; j < 8; ++j) t[j] = f2bf(pr[c * 32 + qd * 8 + j] * SCALE);
      pf[mt][c] = t;
    }
  }

  // KV fragments: B[k=m][n=e], e = 16*wm + nn, m = c*32 + qd*8 + j (dup over wl).
  const float* kvb = kv + (size_t)bh * (64 * 256);
  bf8v kvf[8];
#pragma unroll
  for (int c = 0; c < 8; ++c) {
    const float* src = kvb + (size_t)(16 * wm + nn) * 256 + c * 32 + qd * 8;
    bf8v t;
#pragma unroll
    for (int j = 0; j < 8; ++j) t[j] = f2bf(src[j]);
    kvf[c] = t;
  }

  if (tid < 256) ksume[tid] = ksm[bh * 256 + tid] + 1e-6f;  // Z_EPS

  auto stage = [&](int buf, const f4v* qq) {
    __bf16* qtb = &qt[buf][0];
#pragma unroll
    for (int rr = 0; rr < 2; ++rr) {
      bf4v a;
#pragma unroll
      for (int j = 0; j < 4; ++j) a[j] = f2bf(qq[rr][j]);
      *(bf4v*)&qtb[(r0 + 32 * rr) * 72 + c0] = a;
    }
  };

  stage(0, qr[0]);
  barrier_lgkm();  // qt0 + ksume visible

#pragma unroll
  for (int t = 0; t < 8; ++t) {
    const int cur = t & 1;
    if (t + 2 < 8) {
      qr[cur][0] = *(const f4v*)gq;  qr[cur][1] = *(const f4v*)(gq + RSTEP);
      gq += TSTEP;
    }

    // ---- GEMM3': C[m][l] = P . q^T ; phi ; den partial ; write qf[l][m] ----
    {
      const __bf16* qtb = &qt[cur][0];
#pragma unroll
      for (int li = 0; li < 2; ++li) {
        const int lt = lt0 + li;
        bf8v b0 = *(const bf8v*)&qtb[(lt * 16 + nn) * 72 + qd * 8];
        bf8v b1 = *(const bf8v*)&qtb[(lt * 16 + nn) * 72 + 32 + qd * 8];
        float dpart = 0.f;  // lane's col l = lt*16+nn
#pragma unroll
        for (int mt = 0; mt < 4; ++mt) {
          f4v cc = (f4v){0.f, 0.f, 0.f, 0.f};
          cc = MFMA16(pf[mt][0], b0, cc);
          cc = MFMA16(pf[mt][1], b1, cc);
          // lane holds rows m = 64wm+mt*16+4qd+r, col l = lt*16+nn
          bf4v pk4;
#pragma unroll
          for (int r = 0; r < 4; ++r) {
            float ph = fmaxf(cc[r], 0.f) + 1e-3f;
            dpart += ph * ksume[64 * wm + mt * 16 + 4 * qd + r];
            pk4[r] = f2bf(ph);
          }
          *(bf4v*)&qf[(lt * 16 + nn) * 264 + 64 * wm + mt * 16 + 4 * qd] = pk4;
        }
        dpart += __shfl_xor(dpart, 16, 64);
        dpart += __shfl_xor(dpart, 32, 64);
        if (lane < 16) denp[wm * 64 + lt * 16 + lane] = dpart;
      }
    }
    barrier_lgkm();  // qf + denp visible

    // ---- GEMM4: out[l][e] = qf . KV, 2 independent MFMA chains, store ----
#pragma unroll
    for (int li = 0; li < 2; ++li) {
      const int lt = lt0 + li;
      f4v co0 = (f4v){0.f, 0.f, 0.f, 0.f};
      f4v co1 = (f4v){0.f, 0.f, 0.f, 0.f};
#pragma unroll
      for (int c = 0; c < 4; ++c) {
        bf8v afa = *(const bf8v*)&qf[(lt * 16 + nn) * 264 + c * 32 + qd * 8];
        bf8v afb = *(const bf8v*)&qf[(lt * 16 + nn) * 264 + (c + 4) * 32 + qd * 8];
        co0 = MFMA16(afa, kvf[c], co0);
        co1 = MFMA16(afb, kvf[c + 4], co1);
      }
      f4v d0 = *(const f4v*)&denp[0 * 64 + lt * 16 + 4 * qd];
      f4v d1 = *(const f4v*)&denp[1 * 64 + lt * 16 + 4 * qd];
      f4v d2 = *(const f4v*)&denp[2 * 64 + lt * 16 + 4 * qd];
      f4v d3 = *(const f4v*)&denp[3 * 64 + lt * 16 + 4 * qd];
#pragma unroll
      for (int r = 0; r < 4; ++r) {
        int lrel = lt * 16 + 4 * qd + r;
        int labs = l0 + t * 64 + lrel;
        float rden = 1.f / (d0[r] + d1[r] + d2[r] + d3[r]);
        out[((size_t)((size_t)b * LL + labs) * HH + h) * EE + 16 * wm + nn] =
            (co0[r] + co1[r]) * rden;
      }
    }

    if (t + 1 < 8) {
      stage(cur ^ 1, qr[cur ^ 1]);
      barrier_lgkm();  // qt(t+1) visible; also fences qf/denp WAR
    }
  }
}

extern "C" void kernel_launch(void* const* d_in, const int* in_sizes, int n_in,
                              void* d_out, int out_size, void* d_ws, size_t ws_size,
                              hipStream_t stream) {
  (void)in_sizes; (void)n_in; (void)out_size;
  const float* q = (const float*)d_in[0];
  const float* k = (const float*)d_in[1];
  const float* v = (const float*)d_in[2];
  const float* p = (const float*)d_in[3];
  float* ws = (float*)d_ws;
  float* out = (float*)d_out;

  dim3 grid(8, 64), blk(512);
  if (ws_size >= WS_PART_BYTES) {
    float* pkv = ws;
    float* pks = ws + PKV_ELEMS;
    float* kvp = ws + PKV_ELEMS + PKS_ELEMS;
    float* ksp = kvp + KV_ELEMS;
    k1_kv<<<grid, blk, 0, stream>>>(k, v, p, pkv, pks, nullptr, nullptr, 1);
    k2_red<<<dim3(1040), dim3(256), 0, stream>>>(pkv, pks, kvp, ksp);
    k3_out<<<grid, blk, 0, stream>>>(q, p, kvp, ksp, out);
  } else if (ws_size >= WS_ATOMIC_BYTES) {
    float* kvp = ws;
    float* ksp = ws + KV_ELEMS;
    hipMemsetAsync(d_ws, 0, WS_ATOMIC_BYTES, stream);
    k1_kv<<<grid, blk, 0, stream>>>(k, v, p, nullptr, nullptr, kvp, ksp, 0);
    k3_out<<<grid, blk, 0, stream>>>(q, p, kvp, ksp, out);
  }
}

// Round 4
// 307.709 us; speedup vs baseline: 1.2236x; 1.2236x over previous
//
#include <hip/hip_runtime.h>

// FastAttention (Performer linear attention), MI355X gfx950.
// B=4 L=4096 H=16 D=E=64 M=256, all fp32 in/out. bf16 MFMA internally.
//
// R4: attack the per-iteration serial LDS chain (R0-R3 showed schedule and
// occupancy changes are all neutral; VALUBusy*waves == VALU work => ~90% of
// each iteration is LDS-latency stall).
//  - V stored TRANSPOSED in LDS (vtT[e][l]) -> GEMM2 B-operand is one
//    ds_read_b128 instead of 64 scalar ds_read_u16 per thread per iter.
//  - Tile strides 72/264 -> 76/268 (row stride == 6 mod 32 dwords): b128
//    row-indexed-by-lane reads go from ~4-8-way bank conflicts to <=2-way.
//  - f2bf: native cast (v_cvt_pk_bf16_f32) instead of manual RNE bit-twiddle.
//  - k3: ksume hoisted to 4 f4v registers (kills 32 LDS gathers/iter).
//  - __launch_bounds__(512,3): VGPR budget ~170, no spill possible.

#define LL 4096
#define HH 16
#define DD 64
#define EE 64
#define MM 256
#define SCALE 0.35355339059327378f  // 64^-0.25

typedef __attribute__((ext_vector_type(8))) __bf16 bf8v;
typedef __attribute__((ext_vector_type(4))) __bf16 bf4v;
typedef __attribute__((ext_vector_type(4))) float f4v;

__device__ __forceinline__ __bf16 f2bf(float f) { return (__bf16)f; }  // RNE cvt

// Barrier with LDS-visibility only: does NOT drain vmcnt, so prefetched global
// loads stay in flight across it.
__device__ __forceinline__ void barrier_lgkm() {
  asm volatile("s_waitcnt lgkmcnt(0)" ::: "memory");
  __builtin_amdgcn_s_barrier();
  asm volatile("" ::: "memory");
}

#define MFMA16(a, b, c) __builtin_amdgcn_mfma_f32_16x16x32_bf16(a, b, c, 0, 0, 0)

// ws layout (floats), partial path:
//   [ pkv: 8 chunk * 64 bh * 64 e * 256 m ][ pks: 8 * 64 * 256 ]
//   [ kv : 64 bh * 64 e * 256 m ][ ks: 64 * 256 ]
#define PKV_ELEMS (8ull * 64 * 64 * 256)  // 8,388,608
#define PKS_ELEMS (8ull * 64 * 256)       //   131,072
#define KV_ELEMS (64ull * 64 * 256)       // 1,048,576
#define KS_ELEMS (64ull * 256)            //    16,384
#define WS_PART_BYTES ((PKV_ELEMS + PKS_ELEMS + KV_ELEMS + KS_ELEMS) * 4)
#define WS_ATOMIC_BYTES ((KV_ELEMS + KS_ELEMS) * 4)

// LDS arena (bytes): kt [2][64*76]bf16 = 19456 | vtT [2][64*76]bf16 = 19456
// | kft [256*76]bf16 = 38912 -> total 77824 (<= 80 KB for 2 blocks/CU).
// Epilogue reuses bytes [0, 66560) as float [64 e][260 m-padded].
#define ARENA_BYTES 77824
#define KT_OFF 0
#define VT_OFF 19456
#define KFT_OFF 38912

// ---------------------------------------------------------------------------
// Kernel 1: build KV and Ksum (per-chunk partials, or atomic fallback).
// grid (8 chunks, 64 bh), 512 threads (8 waves). 8 iters of 64 rows.
// Per wave: m-band [32*w, 32*w+32).
// Loop: {stage next tile from regs; issue loads t+2; GEMM1+GEMM2; barrier}.
// ---------------------------------------------------------------------------
__global__ __launch_bounds__(512, 3)
void k1_kv(const float* __restrict__ kin, const float* __restrict__ vin,
           const float* __restrict__ pin,
           float* __restrict__ pkv, float* __restrict__ pks,
           float* __restrict__ kv, float* __restrict__ ks, int partials) {
  __shared__ alignas(16) char arena[ARENA_BYTES];
  __bf16* ktA[2] = {(__bf16*)(arena + KT_OFF), (__bf16*)(arena + KT_OFF) + 64 * 76};
  __bf16* vtA[2] = {(__bf16*)(arena + VT_OFF), (__bf16*)(arena + VT_OFF) + 64 * 76};
  __bf16* kft = (__bf16*)(arena + KFT_OFF);

  const int tid = threadIdx.x;
  const int w = tid >> 6;      // wave 0..7, m-band 32*w
  const int lane = tid & 63;
  const int qd = lane >> 4;
  const int nn = lane & 15;
  const int bh = blockIdx.y;
  const int b = bh >> 4, h = bh & 15;
  const int l0 = blockIdx.x * 512;

  const size_t bhbase = (size_t)b * LL * HH * DD + (size_t)h * DD;
  // staging map: 16 threads cover one 256B row; each thread owns rows r0, r0+32.
  const int r0 = tid >> 4;          // 0..31
  const int c0 = (tid & 15) * 4;    // float col 0..60

  const float* gk = kin + bhbase + (size_t)(l0 + r0) * (HH * DD) + c0;
  const float* gv = vin + bhbase + (size_t)(l0 + r0) * (HH * DD) + c0;
  const size_t RSTEP = (size_t)32 * HH * DD;  // +32 rows
  const size_t TSTEP = (size_t)64 * HH * DD;  // +64 rows (next tile)

  // ---- issue tiles 0,1 (two reg sets: c* = to stage next, n* = in flight) ----
  f4v kc0 = *(const f4v*)gk, kc1 = *(const f4v*)(gk + RSTEP);
  f4v vc0 = *(const f4v*)gv, vc1 = *(const f4v*)(gv + RSTEP);
  gk += TSTEP; gv += TSTEP;
  f4v kn0 = *(const f4v*)gk, kn1 = *(const f4v*)(gk + RSTEP);
  f4v vn0 = *(const f4v*)gv, vn1 = *(const f4v*)(gv + RSTEP);
  gk += TSTEP; gv += TSTEP;

  // P fragments (B-operand of GEMM1): rows m = 32*w + mt*16 + nn, k d = c*32+qd*8+j.
  bf8v pf[2][2];
#pragma unroll
  for (int mt = 0; mt < 2; ++mt) {
    const float* pr = pin + (size_t)(32 * w + mt * 16 + nn) * DD;
#pragma unroll
    for (int c = 0; c < 2; ++c) {
      bf8v t;
#pragma unroll
      for (int j = 0; j < 8; ++j) t[j] = f2bf(pr[c * 32 + qd * 8 + j] * SCALE);
      pf[mt][c] = t;
    }
  }

  f4v acc[2][4];  // [mt][et]: C rows m = 32w+mt*16+4qd+r, cols e = et*16+nn
#pragma unroll
  for (int i = 0; i < 2; ++i)
#pragma unroll
    for (int j = 0; j < 4; ++j) acc[i][j] = (f4v){0.f, 0.f, 0.f, 0.f};
  float ksum[2] = {0.f, 0.f};

  // stage k natural [l][d] (b64 write) + v transposed [e][l] (4 u16 writes/row)
  auto stage = [&](int buf, f4v k0, f4v k1, f4v v0, f4v v1) {
    __bf16* ktb = ktA[buf];
    __bf16* vtb = vtA[buf];
    bf4v a0, a1;
#pragma unroll
    for (int j = 0; j < 4; ++j) { a0[j] = f2bf(k0[j]); a1[j] = f2bf(k1[j]); }
    *(bf4v*)&ktb[r0 * 76 + c0] = a0;
    *(bf4v*)&ktb[(r0 + 32) * 76 + c0] = a1;
#pragma unroll
    for (int j = 0; j < 4; ++j) {
      vtb[(c0 + j) * 76 + r0] = f2bf(v0[j]);
      vtb[(c0 + j) * 76 + r0 + 32] = f2bf(v1[j]);
    }
  };

  auto gemm12 = [&](int buf) {
    const __bf16* ktb = ktA[buf];
    const __bf16* vtb = vtA[buf];
    // GEMM1: C[l][m] = kt . P^T ; phi ; ksum ; write kft[m][l] (own band, b64)
#pragma unroll
    for (int lt = 0; lt < 4; ++lt) {
      bf8v a0 = *(const bf8v*)&ktb[(lt * 16 + nn) * 76 + qd * 8];
      bf8v a1 = *(const bf8v*)&ktb[(lt * 16 + nn) * 76 + 32 + qd * 8];
#pragma unroll
      for (int mt = 0; mt < 2; ++mt) {
        f4v cc = (f4v){0.f, 0.f, 0.f, 0.f};
        cc = MFMA16(a0, pf[mt][0], cc);
        cc = MFMA16(a1, pf[mt][1], cc);
        // lane holds rows l = lt*16+4qd+r, col m = 32w+mt*16+nn
        bf4v pk4;
#pragma unroll
        for (int r = 0; r < 4; ++r) {
          float ph = fmaxf(cc[r], 0.f) + 1e-3f;
          ksum[mt] += ph;  // fp32, pre-rounding
          pk4[r] = f2bf(ph);
        }
        *(bf4v*)&kft[(32 * w + mt * 16 + nn) * 76 + lt * 16 + qd * 4] = pk4;
      }
    }
    // GEMM2: acc[m][e] += kft(own band) . v ; B-fragment = one b128 from vtT
#pragma unroll
    for (int c = 0; c < 2; ++c) {
      bf8v af0 = *(const bf8v*)&kft[(32 * w + nn) * 76 + c * 32 + qd * 8];
      bf8v af1 = *(const bf8v*)&kft[(32 * w + 16 + nn) * 76 + c * 32 + qd * 8];
#pragma unroll
      for (int et = 0; et < 4; ++et) {
        bf8v bv = *(const bf8v*)&vtb[(et * 16 + nn) * 76 + c * 32 + qd * 8];
        acc[0][et] = MFMA16(af0, bv, acc[0][et]);
        acc[1][et] = MFMA16(af1, bv, acc[1][et]);
      }
    }
  };

  // prologue: stage tile 0, make visible
  stage(0, kc0, kc1, vc0, vc1);
  barrier_lgkm();

#pragma unroll
  for (int t = 0; t < 8; ++t) {
    const int cur = t & 1;
    // rotate: n-regs (tile t+1) -> stage; issue loads for t+2 into freed regs
    if (t + 1 < 8) {
      kc0 = kn0; kc1 = kn1; vc0 = vn0; vc1 = vn1;
      if (t + 2 < 8) {
        kn0 = *(const f4v*)gk; kn1 = *(const f4v*)(gk + RSTEP);
        vn0 = *(const f4v*)gv; vn1 = *(const f4v*)(gv + RSTEP);
        gk += TSTEP; gv += TSTEP;
      }
      stage(cur ^ 1, kc0, kc1, vc0, vc1);  // WAR-safe: buf read finished last iter
    }
    gemm12(cur);
    barrier_lgkm();
  }

  // ---- epilogue ----
  if (partials) {
    float* ep = (float*)arena;  // [64 e][260] fp32
#pragma unroll
    for (int mt = 0; mt < 2; ++mt)
#pragma unroll
      for (int et = 0; et < 4; ++et)
        *(f4v*)&ep[(et * 16 + nn) * 260 + 32 * w + mt * 16 + 4 * qd] = acc[mt][et];
    barrier_lgkm();
    // coalesced readback + dense stores: consecutive lanes -> consecutive f4v
    float* dst = pkv + (size_t)(blockIdx.x * 64 + bh) * (64 * 256);
#pragma unroll
    for (int rr = 0; rr < 8; ++rr) {
      int f = tid + 512 * rr;       // 0..4095
      int e = f >> 6;
      int m4 = f & 63;
      f4v val = *(const f4v*)&ep[e * 260 + m4 * 4];
      ((f4v*)dst)[f] = val;
    }
#pragma unroll
    for (int mt = 0; mt < 2; ++mt) {
      float s = ksum[mt];
      s += __shfl_xor(s, 16, 64);
      s += __shfl_xor(s, 32, 64);
      if (lane < 16)
        pks[(size_t)(blockIdx.x * 64 + bh) * 256 + 32 * w + mt * 16 + lane] = s;
    }
  } else {
    float* kvb = kv + (size_t)bh * (64 * 256);
#pragma unroll
    for (int mt = 0; mt < 2; ++mt)
#pragma unroll
      for (int et = 0; et < 4; ++et)
#pragma unroll
        for (int r = 0; r < 4; ++r) {
          int m = 32 * w + mt * 16 + 4 * qd + r;
          int e = et * 16 + nn;
          atomicAdd(&kvb[e * 256 + m], acc[mt][et][r]);
        }
#pragma unroll
    for (int mt = 0; mt < 2; ++mt) {
      float s = ksum[mt];
      s += __shfl_xor(s, 16, 64);
      s += __shfl_xor(s, 32, 64);
      if (lane < 16) atomicAdd(&ks[bh * 256 + 32 * w + mt * 16 + lane], s);
    }
  }
}

// ---------------------------------------------------------------------------
// Kernel 2: reduce 8 chunk-partials -> final KV / Ksum. Pure streaming.
// ---------------------------------------------------------------------------
__global__ __launch_bounds__(256)
void k2_red(const float* __restrict__ pkv, const float* __restrict__ pks,
            float* __restrict__ kv, float* __restrict__ ks) {
  const int idx = blockIdx.x * 256 + threadIdx.x;
  if (idx < 262144) {
    f4v s = (f4v){0.f, 0.f, 0.f, 0.f};
#pragma unroll
    for (int x = 0; x < 8; ++x) s += ((const f4v*)pkv)[(size_t)x * 262144 + idx];
    ((f4v*)kv)[idx] = s;
  } else {
    const int j = idx - 262144;  // < 4096
    f4v s = (f4v){0.f, 0.f, 0.f, 0.f};
#pragma unroll
    for (int x = 0; x < 8; ++x) s += ((const f4v*)pks)[x * 4096 + j];
    ((f4v*)ks)[j] = s;
  }
}

// ---------------------------------------------------------------------------
// Kernel 3: out = (phi(q) @ KV) / (phi(q) . (Ksum+1e-6)).
// grid (8, 64), 512 threads (8 waves = wm 0..3 x wl 0..1), 8 iters of 64 rows.
// qt stride 76, qf stride 268 (conflict-free b128), ksume hoisted to regs.
// ---------------------------------------------------------------------------
__global__ __launch_bounds__(512, 3)
void k3_out(const float* __restrict__ qin, const float* __restrict__ pin,
            const float* __restrict__ kv, const float* __restrict__ ksm,
            float* __restrict__ out) {
  __shared__ __bf16 qt[2][64 * 76];  // q tile [l][d]
  __shared__ __bf16 qf[64 * 268];    // phi(q) [l][m]
  __shared__ float denp[256];        // den partials [wm][l]

  const int tid = threadIdx.x;
  const int w = tid >> 6;
  const int wm = w & 3;
  const int wl = w >> 2;
  const int lane = tid & 63;
  const int qd = lane >> 4;
  const int nn = lane & 15;
  const int bh = blockIdx.y;
  const int b = bh >> 4, h = bh & 15;
  const int l0 = blockIdx.x * 512;
  const int lt0 = 2 * wl;

  const size_t bhbase = (size_t)b * LL * HH * DD + (size_t)h * DD;
  const int r0 = tid >> 4;
  const int c0 = (tid & 15) * 4;

  const float* gq = qin + bhbase + (size_t)(l0 + r0) * (HH * DD) + c0;
  const size_t RSTEP = (size_t)32 * HH * DD;
  const size_t TSTEP = (size_t)64 * HH * DD;

  // ---- issue q tiles 0,1 ----
  f4v qc0 = *(const f4v*)gq, qc1 = *(const f4v*)(gq + RSTEP);
  gq += TSTEP;
  f4v qn0 = *(const f4v*)gq, qn1 = *(const f4v*)(gq + RSTEP);
  gq += TSTEP;

  // P fragments (A-operand of GEMM3': rows m = 64*wm + mt*16 + nn).
  bf8v pf[4][2];
#pragma unroll
  for (int mt = 0; mt < 4; ++mt) {
    const float* pr = pin + (size_t)(64 * wm + mt * 16 + nn) * DD;
#pragma unroll
    for (int c = 0; c < 2; ++c) {
      bf8v t;
#pragma unroll
      for (int j = 0; j < 8; ++j) t[j] = f2bf(pr[c * 32 + qd * 8 + j] * SCALE);
      pf[mt][c] = t;
    }
  }

  // KV fragments: B[k=m][n=e], e = 16*wm + nn, m = c*32 + qd*8 + j (dup over wl).
  const float* kvb = kv + (size_t)bh * (64 * 256);
  bf8v kvf[8];
#pragma unroll
  for (int c = 0; c < 8; ++c) {
    const float* src = kvb + (size_t)(16 * wm + nn) * 256 + c * 32 + qd * 8;
    bf8v t;
#pragma unroll
    for (int j = 0; j < 8; ++j) t[j] = f2bf(src[j]);
    kvf[c] = t;
  }

  // ksume hoisted: lane needs m = 64wm + mt*16 + 4qd + r  (4 f4v registers)
  f4v ke[4];
#pragma unroll
  for (int mt = 0; mt < 4; ++mt) {
    f4v t = *(const f4v*)&ksm[bh * 256 + 64 * wm + mt * 16 + 4 * qd];
    ke[mt] = t + (f4v){1e-6f, 1e-6f, 1e-6f, 1e-6f};  // Z_EPS
  }

  auto stage = [&](int buf, f4v q0, f4v q1) {
    __bf16* qtb = &qt[buf][0];
    bf4v a0, a1;
#pragma unroll
    for (int j = 0; j < 4; ++j) { a0[j] = f2bf(q0[j]); a1[j] = f2bf(q1[j]); }
    *(bf4v*)&qtb[r0 * 76 + c0] = a0;
    *(bf4v*)&qtb[(r0 + 32) * 76 + c0] = a1;
  };

  stage(0, qc0, qc1);
  barrier_lgkm();

#pragma unroll
  for (int t = 0; t < 8; ++t) {
    const int cur = t & 1;

    // ---- GEMM3': C[m][l] = P . q^T ; phi ; den partial ; write qf[l][m] ----
    {
      const __bf16* qtb = &qt[cur][0];
#pragma unroll
      for (int li = 0; li < 2; ++li) {
        const int lt = lt0 + li;
        bf8v b0 = *(const bf8v*)&qtb[(lt * 16 + nn) * 76 + qd * 8];
        bf8v b1 = *(const bf8v*)&qtb[(lt * 16 + nn) * 76 + 32 + qd * 8];
        float dpart = 0.f;  // lane's col l = lt*16+nn
#pragma unroll
        for (int mt = 0; mt < 4; ++mt) {
          f4v cc = (f4v){0.f, 0.f, 0.f, 0.f};
          cc = MFMA16(pf[mt][0], b0, cc);
          cc = MFMA16(pf[mt][1], b1, cc);
          // lane holds rows m = 64wm+mt*16+4qd+r, col l = lt*16+nn
          bf4v pk4;
#pragma unroll
          for (int r = 0; r < 4; ++r) {
            float ph = fmaxf(cc[r], 0.f) + 1e-3f;
            dpart += ph * ke[mt][r];
            pk4[r] = f2bf(ph);
          }
          *(bf4v*)&qf[(lt * 16 + nn) * 268 + 64 * wm + mt * 16 + 4 * qd] = pk4;
        }
        dpart += __shfl_xor(dpart, 16, 64);
        dpart += __shfl_xor(dpart, 32, 64);
        if (lane < 16) denp[wm * 64 + lt * 16 + lane] = dpart;
      }
    }
    barrier_lgkm();  // qf + denp visible

    // ---- GEMM4: out[l][e] = qf . KV, 2 independent MFMA chains, store ----
#pragma unroll
    for (int li = 0; li < 2; ++li) {
      const int lt = lt0 + li;
      f4v co0 = (f4v){0.f, 0.f, 0.f, 0.f};
      f4v co1 = (f4v){0.f, 0.f, 0.f, 0.f};
#pragma unroll
      for (int c = 0; c < 4; ++c) {
        bf8v afa = *(const bf8v*)&qf[(lt * 16 + nn) * 268 + c * 32 + qd * 8];
        bf8v afb = *(const bf8v*)&qf[(lt * 16 + nn) * 268 + (c + 4) * 32 + qd * 8];
        co0 = MFMA16(afa, kvf[c], co0);
        co1 = MFMA16(afb, kvf[c + 4], co1);
      }
      f4v d0 = *(const f4v*)&denp[0 * 64 + lt * 16 + 4 * qd];
      f4v d1 = *(const f4v*)&denp[1 * 64 + lt * 16 + 4 * qd];
      f4v d2 = *(const f4v*)&denp[2 * 64 + lt * 16 + 4 * qd];
      f4v d3 = *(const f4v*)&denp[3 * 64 + lt * 16 + 4 * qd];
#pragma unroll
      for (int r = 0; r < 4; ++r) {
        int lrel = lt * 16 + 4 * qd + r;
        int labs = l0 + t * 64 + lrel;
        float rden = 1.f / (d0[r] + d1[r] + d2[r] + d3[r]);
        out[((size_t)((size_t)b * LL + labs) * HH + h) * EE + 16 * wm + nn] =
            (co0[r] + co1[r]) * rden;
      }
    }

    if (t + 1 < 8) {
      qc0 = qn0; qc1 = qn1;
      if (t + 2 < 8) {
        qn0 = *(const f4v*)gq; qn1 = *(const f4v*)(gq + RSTEP);
        gq += TSTEP;
      }
      stage(cur ^ 1, qc0, qc1);
      barrier_lgkm();  // qt(t+1) visible; also fences qf/denp WAR
    }
  }
}

extern "C" void kernel_launch(void* const* d_in, const int* in_sizes, int n_in,
                              void* d_out, int out_size, void* d_ws, size_t ws_size,
                              hipStream_t stream) {
  (void)in_sizes; (void)n_in; (void)out_size;
  const float* q = (const float*)d_in[0];
  const float* k = (const float*)d_in[1];
  const float* v = (const float*)d_in[2];
  const float* p = (const float*)d_in[3];
  float* ws = (float*)d_ws;
  float* out = (float*)d_out;

  dim3 grid(8, 64), blk(512);
  if (ws_size >= WS_PART_BYTES) {
    float* pkv = ws;
    float* pks = ws + PKV_ELEMS;
    float* kvp = ws + PKV_ELEMS + PKS_ELEMS;
    float* ksp = kvp + KV_ELEMS;
    k1_kv<<<grid, blk, 0, stream>>>(k, v, p, pkv, pks, nullptr, nullptr, 1);
    k2_red<<<dim3(1040), dim3(256), 0, stream>>>(pkv, pks, kvp, ksp);
    k3_out<<<grid, blk, 0, stream>>>(q, p, kvp, ksp, out);
  } else if (ws_size >= WS_ATOMIC_BYTES) {
    float* kvp = ws;
    float* ksp = ws + KV_ELEMS;
    hipMemsetAsync(d_ws, 0, WS_ATOMIC_BYTES, stream);
    k1_kv<<<grid, blk, 0, stream>>>(k, v, p, nullptr, nullptr, kvp, ksp, 0);
    k3_out<<<grid, blk, 0, stream>>>(q, p, kvp, ksp, out);
  }
}